// Round 5
// baseline (1131.971 us; speedup 1.0000x reference)
//
#include <hip/hip_runtime.h>
#include <hip/hip_fp16.h>

#define EPSC  1e-4f
#define THETA 0.04f
#define WCH   1024    // phase-1 edges per wave-grab
#define XEB   1024    // expand edges per block

// ws layout:
//   float[0..7] softmax(w), float[8..39] m, float[40] b
//   byte 256:  int ctr[8]
//   byte 4096: slices = 8 heads x N x 16 halves (32 B per node per head)
//   then:      partial = 8 planes x EP floats

__device__ __forceinline__ void write_params(const float* w, const float* r_dist,
                                             const float* b, float* ws) {
    float wm = w[0];
    #pragma unroll
    for (int i = 1; i < 8; ++i) wm = fmaxf(wm, w[i]);
    float e[8]; float s = 0.f;
    #pragma unroll
    for (int i = 0; i < 8; ++i) { e[i] = __expf(w[i] - wm); s += e[i]; }
    float inv = 1.0f / s;
    #pragma unroll
    for (int i = 0; i < 8; ++i) ws[i] = e[i] * inv;
    float acc = 0.f;
    for (int c = 0; c < 32; ++c) {
        acc += fabsf(r_dist[c] + EPSC) + EPSC;
        ws[8 + c] = fmaxf(acc, 0.f);
    }
    ws[40] = b[0];
}

__global__ void param_kernel(const float* __restrict__ w,
                             const float* __restrict__ r_dist,
                             const float* __restrict__ b,
                             float* __restrict__ ws) {
    if (blockIdx.x == 0 && threadIdx.x == 0) write_params(w, r_dist, b, ws);
}

// grid (ceil(N/256), 8): head c = blockIdx.y, node n fastest -> coalesced writes
__global__ __launch_bounds__(256) void convert_kernel(
    const float* __restrict__ h,
    const float* __restrict__ w,
    const float* __restrict__ r_dist,
    const float* __restrict__ b,
    float* __restrict__ ws,
    unsigned* __restrict__ slices,
    int* __restrict__ ctr,
    int N) {
    const int c = blockIdx.y;
    const int n = blockIdx.x * 256 + threadIdx.x;
    if (blockIdx.x == 0 && c == 0) {
        if (threadIdx.x == 0) write_params(w, r_dist, b, ws);
        if (threadIdx.x < 8) ctr[threadIdx.x] = 0;
    }
    if (n < N) {
        const float4* p = (const float4*)(h + (size_t)n * 128 + c * 16);
        float4 v0 = p[0], v1 = p[1], v2 = p[2], v3 = p[3];
        __half2 x;
        uint4 o0, o1;
        x = __floats2half2_rn(v0.x, v0.y); o0.x = *(unsigned*)&x;
        x = __floats2half2_rn(v0.z, v0.w); o0.y = *(unsigned*)&x;
        x = __floats2half2_rn(v1.x, v1.y); o0.z = *(unsigned*)&x;
        x = __floats2half2_rn(v1.z, v1.w); o0.w = *(unsigned*)&x;
        x = __floats2half2_rn(v2.x, v2.y); o1.x = *(unsigned*)&x;
        x = __floats2half2_rn(v2.z, v2.w); o1.y = *(unsigned*)&x;
        x = __floats2half2_rn(v3.x, v3.y); o1.z = *(unsigned*)&x;
        x = __floats2half2_rn(v3.z, v3.w); o1.w = *(unsigned*)&x;
        unsigned* dp = slices + ((size_t)c * N + n) * 8;
        *(uint4*)(dp)     = o0;
        *(uint4*)(dp + 4) = o1;
    }
}

__device__ __forceinline__ float acc_sq8(uint4 a, uint4 b) {
    float ss = 0.f;
    const unsigned* pa = &a.x;
    const unsigned* pb = &b.x;
    #pragma unroll
    for (int i = 0; i < 4; ++i) {
        float2 fa = __half22float2(*(const __half2*)&pa[i]);
        float2 fb = __half22float2(*(const __half2*)&pb[i]);
        float d0 = fa.x - fb.x, d1 = fa.y - fb.y;
        ss += d0 * d0 + d1 * d1;
    }
    return ss;
}

// phase 1: one thread = one edge-class. No LDS, no shfl-reduce, no barriers.
__global__ __launch_bounds__(256) void phase1_kernel(
    const unsigned* __restrict__ slices,
    const int* __restrict__ src,
    const int* __restrict__ dst,
    const float* __restrict__ wsf,
    float* __restrict__ partial,
    int* __restrict__ ctr,
    int E, int N, long long EP, int nchunk) {
    int xcc;
    asm volatile("s_getreg_b32 %0, hwreg(HW_REG_XCC_ID)" : "=s"(xcc));
    xcc &= 7;
    const int lane = threadIdx.x & 63;

    for (int k = 0; k < 8; ++k) {
        const int c = (xcc + k) & 7;            // own class first, then steal
        const float wc = wsf[c];
        const uint4* sp = (const uint4*)(slices + (size_t)c * N * 8);
        float* pplane = partial + (size_t)c * EP;
        for (;;) {
            int chunk = 0;
            if (lane == 0) chunk = atomicAdd(&ctr[c], 1);
            chunk = __shfl(chunk, 0);           // wave-wide broadcast
            if (chunk >= nchunk) break;
            const int e0 = chunk * WCH;
            const int eend = min(e0 + WCH, E);
            #pragma unroll 2
            for (int i = e0 + lane; i < eend; i += 64) {
                const int sn = __builtin_nontemporal_load(src + i);
                const int dn = __builtin_nontemporal_load(dst + i);
                uint4 a0 = sp[(size_t)sn * 2];
                uint4 a1 = sp[(size_t)sn * 2 + 1];
                uint4 b0 = sp[(size_t)dn * 2];
                uint4 b1 = sp[(size_t)dn * 2 + 1];
                float ss = acc_sq8(a0, b0) + acc_sq8(a1, b1);
                __builtin_nontemporal_store(sqrtf(ss) * wc, pplane + i);
            }
        }
    }
}

__device__ __forceinline__ float edge_dist32(float4 a, float4 c, float wgt) {
    float dx = c.x - a.x, dy = c.y - a.y, dz = c.z - a.z, dw = c.w - a.w;
    float ss = dx * dx + dy * dy + dz * dz + dw * dw;
    ss += __shfl_xor(ss, 1);
    ss += __shfl_xor(ss, 2);
    float t = sqrtf(ss) * wgt;
    t += __shfl_xor(t, 4);
    t += __shfl_xor(t, 8);
    t += __shfl_xor(t, 16);
    return t;
}

// phase 2: sum partials (coalesced float4) -> LDS; refine near-boundary edges
__global__ __launch_bounds__(256) void expand_kernel(
    const float* __restrict__ h,
    const float* __restrict__ partial,
    const int* __restrict__ src,
    const int* __restrict__ dst,
    const float* __restrict__ ws,
    float* __restrict__ out,
    int E, long long EP) {
    __shared__ int s_src[XEB];
    __shared__ int s_dst[XEB];
    __shared__ float s_dist[XEB];
    __shared__ float s_w[8];
    __shared__ float s_m[32];
    __shared__ float s_b;

    const int t = threadIdx.x;
    if (t < 8)  s_w[t] = ws[t];
    if (t < 32) s_m[t] = ws[8 + t];
    if (t == 0) s_b = ws[40];

    const long long base = (long long)blockIdx.x * XEB;
    const bool full = (base + XEB <= (long long)E);

    if (full) {
        ((int4*)s_src)[t] = ((const int4*)(src + base))[t];
        ((int4*)s_dst)[t] = ((const int4*)(dst + base))[t];
        float4 acc = make_float4(0.f, 0.f, 0.f, 0.f);
        #pragma unroll
        for (int c = 0; c < 8; ++c) {
            float4 p = *(const float4*)(partial + (size_t)c * EP + base + t * 4);
            acc.x += p.x; acc.y += p.y; acc.z += p.z; acc.w += p.w;
        }
        *(float4*)&s_dist[t * 4] = acc;
    } else {
        for (int i = t; i < XEB; i += 256) {
            long long e = base + i;
            s_src[i] = (e < (long long)E) ? src[e] : 0;
            s_dst[i] = (e < (long long)E) ? dst[e] : 0;
            float d = 0.f;
            if (e < (long long)E) {
                #pragma unroll
                for (int c = 0; c < 8; ++c) d += partial[(size_t)c * EP + e];
            }
            s_dist[i] = d;
        }
    }
    __syncthreads();

    const int lane32 = t & 31;
    const int half32 = (t >> 5) & 1;
    const int group  = t >> 5;
    const float wgt  = s_w[lane32 >> 2];
    const float m_c  = s_m[lane32];
    const float bb   = s_b;

    for (int i = group * 128; i < group * 128 + 128; ++i) {
        const long long e = base + i;
        if (e >= (long long)E) break;
        float margin = s_dist[i] - m_c;
        const bool near = fabsf(margin) < THETA;
        unsigned long long mask = __ballot(near);
        unsigned gm = (unsigned)(mask >> (half32 ? 32 : 0));
        if (gm) {
            const int si = s_src[i], di = s_dst[i];
            float4 a = ((const float4*)(h + (size_t)si * 128))[lane32];
            float4 c = ((const float4*)(h + (size_t)di * 128))[lane32];
            margin = edge_dist32(a, c, wgt) - m_c;
        }
        __builtin_nontemporal_store(1.0f / (margin * margin + bb),
                                    out + (size_t)e * 32 + lane32);
    }
}

// fallback: pure-f32 direct path
__global__ __launch_bounds__(256) void score_kernel_f32(
    const float* __restrict__ h,
    const int* __restrict__ src,
    const int* __restrict__ dst,
    const float* __restrict__ ws,
    float* __restrict__ out,
    int E) {
    __shared__ float s_w[8];
    __shared__ float s_m[32];
    __shared__ float s_b;
    const int t = threadIdx.x;
    if (t < 8)  s_w[t] = ws[t];
    if (t < 32) s_m[t] = ws[8 + t];
    if (t == 0) s_b = ws[40];
    __syncthreads();
    const int lane32 = t & 31;
    const int group  = t >> 5;
    const int gid    = blockIdx.x * 8 + group;
    const int stride = gridDim.x * 8;
    const float wgt  = s_w[lane32 >> 2];
    const float m_c  = s_m[lane32];
    const float bb   = s_b;
    for (int e = gid; e < E; e += stride) {
        const int si = src[e], di = dst[e];
        float4 a = ((const float4*)(h + (size_t)si * 128))[lane32];
        float4 c = ((const float4*)(h + (size_t)di * 128))[lane32];
        float tt = edge_dist32(a, c, wgt);
        float dm = tt - m_c;
        __builtin_nontemporal_store(1.0f / (dm * dm + bb),
                                    out + (size_t)e * 32 + lane32);
    }
}

extern "C" void kernel_launch(void* const* d_in, const int* in_sizes, int n_in,
                              void* d_out, int out_size, void* d_ws, size_t ws_size,
                              hipStream_t stream) {
    const float* h      = (const float*)d_in[0];
    const float* w      = (const float*)d_in[1];
    const float* r_dist = (const float*)d_in[2];
    const float* b      = (const float*)d_in[3];
    const int*   src    = (const int*)d_in[4];
    const int*   dst    = (const int*)d_in[5];
    float* out = (float*)d_out;
    float* ws  = (float*)d_ws;
    const int E = in_sizes[4];
    const int N = in_sizes[0] / 128;

    const long long EP = ((long long)E + 1023) & ~1023LL;
    const size_t slice_off = 4096;
    const size_t slice_bytes = (size_t)8 * N * 32;
    const size_t part_off = slice_off + slice_bytes;
    const size_t need = part_off + (size_t)8 * EP * 4;

    if (ws_size >= need) {
        unsigned* slices = (unsigned*)((char*)d_ws + slice_off);
        float* partial   = (float*)((char*)d_ws + part_off);
        int* ctr         = (int*)((char*)d_ws + 256);
        const int nchunk = (E + WCH - 1) / WCH;

        dim3 cgrid((N + 255) / 256, 8);
        convert_kernel<<<cgrid, 256, 0, stream>>>(h, w, r_dist, b, ws,
                                                  slices, ctr, N);
        phase1_kernel<<<2048, 256, 0, stream>>>(slices, src, dst, ws, partial,
                                                ctr, E, N, EP, nchunk);
        expand_kernel<<<(E + XEB - 1) / XEB, 256, 0, stream>>>(
            h, partial, src, dst, ws, out, E, EP);
    } else {
        param_kernel<<<1, 64, 0, stream>>>(w, r_dist, b, ws);
        score_kernel_f32<<<2048, 256, 0, stream>>>(h, src, dst, ws, out, E);
    }
}

// Round 6
// 382.743 us; speedup vs baseline: 2.9575x; 2.9575x over previous
//
#include <hip/hip_runtime.h>
#include <hip/hip_fp16.h>

#define EPSC  1e-4f
#define THETA 0.04f
#define XEB   1024    // expand edges per block

// ws layout:
//   float[0..7] softmax(w), float[8..39] m, float[40] b
//   byte 4096: slices = 8 heads x N x 16 halves (32 B per node per head)
//   then:      partial = 8 planes x EP floats

__device__ __forceinline__ void write_params(const float* w, const float* r_dist,
                                             const float* b, float* ws) {
    float wm = w[0];
    #pragma unroll
    for (int i = 1; i < 8; ++i) wm = fmaxf(wm, w[i]);
    float e[8]; float s = 0.f;
    #pragma unroll
    for (int i = 0; i < 8; ++i) { e[i] = __expf(w[i] - wm); s += e[i]; }
    float inv = 1.0f / s;
    #pragma unroll
    for (int i = 0; i < 8; ++i) ws[i] = e[i] * inv;
    float acc = 0.f;
    for (int c = 0; c < 32; ++c) {
        acc += fabsf(r_dist[c] + EPSC) + EPSC;
        ws[8 + c] = fmaxf(acc, 0.f);
    }
    ws[40] = b[0];
}

__global__ void param_kernel(const float* __restrict__ w,
                             const float* __restrict__ r_dist,
                             const float* __restrict__ b,
                             float* __restrict__ ws) {
    if (blockIdx.x == 0 && threadIdx.x == 0) write_params(w, r_dist, b, ws);
}

// grid (ceil(N/256), 8): head c = blockIdx.y, node n fastest -> coalesced writes
__global__ __launch_bounds__(256) void convert_kernel(
    const float* __restrict__ h,
    const float* __restrict__ w,
    const float* __restrict__ r_dist,
    const float* __restrict__ b,
    float* __restrict__ ws,
    unsigned* __restrict__ slices,
    int N) {
    const int c = blockIdx.y;
    const int n = blockIdx.x * 256 + threadIdx.x;
    if (blockIdx.x == 0 && c == 0 && threadIdx.x == 0) write_params(w, r_dist, b, ws);
    if (n < N) {
        const float4* p = (const float4*)(h + (size_t)n * 128 + c * 16);
        float4 v0 = p[0], v1 = p[1], v2 = p[2], v3 = p[3];
        __half2 x;
        uint4 o0, o1;
        x = __floats2half2_rn(v0.x, v0.y); o0.x = *(unsigned*)&x;
        x = __floats2half2_rn(v0.z, v0.w); o0.y = *(unsigned*)&x;
        x = __floats2half2_rn(v1.x, v1.y); o0.z = *(unsigned*)&x;
        x = __floats2half2_rn(v1.z, v1.w); o0.w = *(unsigned*)&x;
        x = __floats2half2_rn(v2.x, v2.y); o1.x = *(unsigned*)&x;
        x = __floats2half2_rn(v2.z, v2.w); o1.y = *(unsigned*)&x;
        x = __floats2half2_rn(v3.x, v3.y); o1.z = *(unsigned*)&x;
        x = __floats2half2_rn(v3.z, v3.w); o1.w = *(unsigned*)&x;
        unsigned* dp = slices + ((size_t)c * N + n) * 8;
        *(uint4*)(dp)     = o0;
        *(uint4*)(dp + 4) = o1;
    }
}

__device__ __forceinline__ float acc_sq8(uint4 a, uint4 b) {
    float ss = 0.f;
    const unsigned* pa = &a.x;
    const unsigned* pb = &b.x;
    #pragma unroll
    for (int i = 0; i < 4; ++i) {
        float2 fa = __half22float2(*(const __half2*)&pa[i]);
        float2 fb = __half22float2(*(const __half2*)&pb[i]);
        float d0 = fa.x - fb.x, d1 = fa.y - fb.y;
        ss += d0 * d0 + d1 * d1;
    }
    return ss;
}

// phase 1: static partition, zero atomics, zero LDS, zero barriers.
// class c = blockIdx&7 (round-robin XCD dispatch pins slice c to one L2;
// correctness does not depend on the mapping). Block bl covers a contiguous
// E/256 range with coalesced idx loads / partial stores.
__global__ __launch_bounds__(256) void phase1_kernel(
    const unsigned* __restrict__ slices,
    const int* __restrict__ src,
    const int* __restrict__ dst,
    const float* __restrict__ wsf,
    float* __restrict__ partial,
    int E, int N, long long EP) {
    const int c    = blockIdx.x & 7;
    const int bl   = blockIdx.x >> 3;
    const int nblk = gridDim.x >> 3;
    const float wc = wsf[c];
    const uint4* sp = (const uint4*)(slices + (size_t)c * N * 8);
    float* pplane = partial + (size_t)c * EP;

    const int per  = (E + nblk - 1) / nblk;
    const int e0   = bl * per;
    const int eend = min(e0 + per, E);

    #pragma unroll 4
    for (int i = e0 + threadIdx.x; i < eend; i += 256) {
        const int sn = __builtin_nontemporal_load(src + i);
        const int dn = __builtin_nontemporal_load(dst + i);
        uint4 a0 = sp[(size_t)sn * 2];
        uint4 a1 = sp[(size_t)sn * 2 + 1];
        uint4 b0 = sp[(size_t)dn * 2];
        uint4 b1 = sp[(size_t)dn * 2 + 1];
        float ss = acc_sq8(a0, b0) + acc_sq8(a1, b1);
        __builtin_nontemporal_store(sqrtf(ss) * wc, pplane + i);
    }
}

__device__ __forceinline__ float edge_dist32(float4 a, float4 c, float wgt) {
    float dx = c.x - a.x, dy = c.y - a.y, dz = c.z - a.z, dw = c.w - a.w;
    float ss = dx * dx + dy * dy + dz * dz + dw * dw;
    ss += __shfl_xor(ss, 1);
    ss += __shfl_xor(ss, 2);
    float t = sqrtf(ss) * wgt;
    t += __shfl_xor(t, 4);
    t += __shfl_xor(t, 8);
    t += __shfl_xor(t, 16);
    return t;
}

// phase 2: sum partials (coalesced float4) -> LDS; refine near-boundary edges
__global__ __launch_bounds__(256) void expand_kernel(
    const float* __restrict__ h,
    const float* __restrict__ partial,
    const int* __restrict__ src,
    const int* __restrict__ dst,
    const float* __restrict__ ws,
    float* __restrict__ out,
    int E, long long EP) {
    __shared__ int s_src[XEB];
    __shared__ int s_dst[XEB];
    __shared__ float s_dist[XEB];
    __shared__ float s_w[8];
    __shared__ float s_m[32];
    __shared__ float s_b;

    const int t = threadIdx.x;
    if (t < 8)  s_w[t] = ws[t];
    if (t < 32) s_m[t] = ws[8 + t];
    if (t == 0) s_b = ws[40];

    const long long base = (long long)blockIdx.x * XEB;
    const bool full = (base + XEB <= (long long)E);

    if (full) {
        ((int4*)s_src)[t] = ((const int4*)(src + base))[t];
        ((int4*)s_dst)[t] = ((const int4*)(dst + base))[t];
        float4 acc = make_float4(0.f, 0.f, 0.f, 0.f);
        #pragma unroll
        for (int c = 0; c < 8; ++c) {
            float4 p = *(const float4*)(partial + (size_t)c * EP + base + t * 4);
            acc.x += p.x; acc.y += p.y; acc.z += p.z; acc.w += p.w;
        }
        *(float4*)&s_dist[t * 4] = acc;
    } else {
        for (int i = t; i < XEB; i += 256) {
            long long e = base + i;
            s_src[i] = (e < (long long)E) ? src[e] : 0;
            s_dst[i] = (e < (long long)E) ? dst[e] : 0;
            float d = 0.f;
            if (e < (long long)E) {
                #pragma unroll
                for (int c = 0; c < 8; ++c) d += partial[(size_t)c * EP + e];
            }
            s_dist[i] = d;
        }
    }
    __syncthreads();

    const int lane32 = t & 31;
    const int half32 = (t >> 5) & 1;
    const int group  = t >> 5;
    const float wgt  = s_w[lane32 >> 2];
    const float m_c  = s_m[lane32];
    const float bb   = s_b;

    for (int i = group * 128; i < group * 128 + 128; ++i) {
        const long long e = base + i;
        if (e >= (long long)E) break;
        float margin = s_dist[i] - m_c;
        const bool near = fabsf(margin) < THETA;
        unsigned long long mask = __ballot(near);
        unsigned gm = (unsigned)(mask >> (half32 ? 32 : 0));
        if (gm) {
            const int si = s_src[i], di = s_dst[i];
            float4 a = ((const float4*)(h + (size_t)si * 128))[lane32];
            float4 c = ((const float4*)(h + (size_t)di * 128))[lane32];
            margin = edge_dist32(a, c, wgt) - m_c;
        }
        __builtin_nontemporal_store(1.0f / (margin * margin + bb),
                                    out + (size_t)e * 32 + lane32);
    }
}

// fallback: pure-f32 direct path
__global__ __launch_bounds__(256) void score_kernel_f32(
    const float* __restrict__ h,
    const int* __restrict__ src,
    const int* __restrict__ dst,
    const float* __restrict__ ws,
    float* __restrict__ out,
    int E) {
    __shared__ float s_w[8];
    __shared__ float s_m[32];
    __shared__ float s_b;
    const int t = threadIdx.x;
    if (t < 8)  s_w[t] = ws[t];
    if (t < 32) s_m[t] = ws[8 + t];
    if (t == 0) s_b = ws[40];
    __syncthreads();
    const int lane32 = t & 31;
    const int group  = t >> 5;
    const int gid    = blockIdx.x * 8 + group;
    const int stride = gridDim.x * 8;
    const float wgt  = s_w[lane32 >> 2];
    const float m_c  = s_m[lane32];
    const float bb   = s_b;
    for (int e = gid; e < E; e += stride) {
        const int si = src[e], di = dst[e];
        float4 a = ((const float4*)(h + (size_t)si * 128))[lane32];
        float4 c = ((const float4*)(h + (size_t)di * 128))[lane32];
        float tt = edge_dist32(a, c, wgt);
        float dm = tt - m_c;
        __builtin_nontemporal_store(1.0f / (dm * dm + bb),
                                    out + (size_t)e * 32 + lane32);
    }
}

extern "C" void kernel_launch(void* const* d_in, const int* in_sizes, int n_in,
                              void* d_out, int out_size, void* d_ws, size_t ws_size,
                              hipStream_t stream) {
    const float* h      = (const float*)d_in[0];
    const float* w      = (const float*)d_in[1];
    const float* r_dist = (const float*)d_in[2];
    const float* b      = (const float*)d_in[3];
    const int*   src    = (const int*)d_in[4];
    const int*   dst    = (const int*)d_in[5];
    float* out = (float*)d_out;
    float* ws  = (float*)d_ws;
    const int E = in_sizes[4];
    const int N = in_sizes[0] / 128;

    const long long EP = ((long long)E + 1023) & ~1023LL;
    const size_t slice_off = 4096;
    const size_t slice_bytes = (size_t)8 * N * 32;
    const size_t part_off = slice_off + slice_bytes;
    const size_t need = part_off + (size_t)8 * EP * 4;

    if (ws_size >= need) {
        unsigned* slices = (unsigned*)((char*)d_ws + slice_off);
        float* partial   = (float*)((char*)d_ws + part_off);

        dim3 cgrid((N + 255) / 256, 8);
        convert_kernel<<<cgrid, 256, 0, stream>>>(h, w, r_dist, b, ws, slices, N);
        phase1_kernel<<<2048, 256, 0, stream>>>(slices, src, dst, ws, partial,
                                                E, N, EP);
        expand_kernel<<<(E + XEB - 1) / XEB, 256, 0, stream>>>(
            h, partial, src, dst, ws, out, E, EP);
    } else {
        param_kernel<<<1, 64, 0, stream>>>(w, r_dist, b, ws);
        score_kernel_f32<<<2048, 256, 0, stream>>>(h, src, dst, ws, out, E);
    }
}

// Round 7
// 249.233 us; speedup vs baseline: 4.5418x; 1.5357x over previous
//
#include <hip/hip_runtime.h>
#include <hip/hip_fp16.h>

#define EPSC  1e-4f
#define THETA 0.04f
#define EPB   2048   // edges per block (512 thr = 16 groups x 128 edges)
#define EPG   128    // edges per 32-lane group

// ws layout: float[0..7] softmax(w), float[8..39] m, float[40] b
//            byte 4096: h16 = N nodes x 128 dims fp16 (256 B/node)

__device__ __forceinline__ void write_params(const float* w, const float* r_dist,
                                             const float* b, float* ws) {
    float wm = w[0];
    #pragma unroll
    for (int i = 1; i < 8; ++i) wm = fmaxf(wm, w[i]);
    float e[8]; float s = 0.f;
    #pragma unroll
    for (int i = 0; i < 8; ++i) { e[i] = __expf(w[i] - wm); s += e[i]; }
    float inv = 1.0f / s;
    #pragma unroll
    for (int i = 0; i < 8; ++i) ws[i] = e[i] * inv;
    float acc = 0.f;
    for (int c = 0; c < 32; ++c) {
        acc += fabsf(r_dist[c] + EPSC) + EPSC;
        ws[8 + c] = fmaxf(acc, 0.f);
    }
    ws[40] = b[0];
}

__global__ void param_kernel(const float* __restrict__ w,
                             const float* __restrict__ r_dist,
                             const float* __restrict__ b,
                             float* __restrict__ ws) {
    if (blockIdx.x == 0 && threadIdx.x == 0) write_params(w, r_dist, b, ws);
}

// h -> fp16, node-major (256B/node). One thread = 8 dims = one uint4 out.
__global__ __launch_bounds__(256) void convert_kernel(
    const float* __restrict__ h,
    const float* __restrict__ w,
    const float* __restrict__ r_dist,
    const float* __restrict__ b,
    float* __restrict__ ws,
    uint4* __restrict__ h16,
    long long nq) {          // nq = N*16 quads
    const long long i = (long long)blockIdx.x * 256 + threadIdx.x;
    if (i == 0) write_params(w, r_dist, b, ws);
    if (i < nq) {
        const float4* p = (const float4*)h + i * 2;
        float4 v0 = p[0], v1 = p[1];
        __half2 x;
        uint4 o;
        x = __floats2half2_rn(v0.x, v0.y); o.x = *(unsigned*)&x;
        x = __floats2half2_rn(v0.z, v0.w); o.y = *(unsigned*)&x;
        x = __floats2half2_rn(v1.x, v1.y); o.z = *(unsigned*)&x;
        x = __floats2half2_rn(v1.z, v1.w); o.w = *(unsigned*)&x;
        h16[i] = o;
    }
}

__device__ __forceinline__ float acc_sq8(uint4 a, uint4 b) {
    float ss = 0.f;
    const unsigned* pa = &a.x;
    const unsigned* pb = &b.x;
    #pragma unroll
    for (int i = 0; i < 4; ++i) {
        float2 fa = __half22float2(*(const __half2*)&pa[i]);
        float2 fb = __half22float2(*(const __half2*)&pb[i]);
        float d0 = fa.x - fb.x, d1 = fa.y - fb.y;
        ss += d0 * d0 + d1 * d1;
    }
    return ss;
}

__device__ __forceinline__ float edge_dist32(float4 a, float4 c, float wgt) {
    float dx = c.x - a.x, dy = c.y - a.y, dz = c.z - a.z, dw = c.w - a.w;
    float ss = dx * dx + dy * dy + dz * dz + dw * dw;
    ss += __shfl_xor(ss, 1);
    ss += __shfl_xor(ss, 2);
    float t = sqrtf(ss) * wgt;
    t += __shfl_xor(t, 4);
    t += __shfl_xor(t, 8);
    t += __shfl_xor(t, 16);
    return t;
}

// One 32-lane group processes TWO edges per iteration:
//   lanes 0-15 own edge A, lanes 16-31 own edge B.
//   Each sub-lane loads one uint4 (16B = 8 dims) of its edge's src and dst
//   -> 4 independent 16B gathers in flight per lane pair, 32 requests/edge.
//   Near-boundary edges refined with the exact f32 path (proven).
__global__ __launch_bounds__(512) void score_kernel(
    const float* __restrict__ h,
    const uint4* __restrict__ h16,
    const int* __restrict__ src,
    const int* __restrict__ dst,
    const float* __restrict__ ws,
    float* __restrict__ out,
    int E) {
    __shared__ int s_src[EPB];
    __shared__ int s_dst[EPB];
    __shared__ float s_w[8];
    __shared__ float s_m[32];
    __shared__ float s_b;

    const int t = threadIdx.x;
    if (t < 8)  s_w[t] = ws[t];
    if (t < 32) s_m[t] = ws[8 + t];
    if (t == 0) s_b = ws[40];

    const long long base = (long long)blockIdx.x * EPB;
    if (base + EPB <= (long long)E) {
        ((int4*)s_src)[t] = ((const int4*)(src + base))[t];   // 512 int4 = 2048 ints
        ((int4*)s_dst)[t] = ((const int4*)(dst + base))[t];
    } else {
        for (int i = t; i < EPB; i += 512) {
            long long e = base + i;
            s_src[i] = (e < (long long)E) ? src[e] : 0;
            s_dst[i] = (e < (long long)E) ? dst[e] : 0;
        }
    }
    __syncthreads();

    const int lane   = t & 31;        // lane within 32-group
    const int sl     = lane & 15;     // sub-lane within 16-half
    const int halfid = lane >> 4;     // 0 = edge A, 1 = edge B
    const int group  = t >> 5;        // 16 groups per block
    const int gsh    = t & 32;        // this group's shift within the wave ballot

    const float wmain = s_w[sl >> 1];     // main path: 2 lanes per head
    const float wref  = s_w[lane >> 2];   // refine path: 4 lanes per head
    const float m_c   = s_m[lane];
    const float bb    = s_b;
    const float4* h32 = (const float4*)h;

    const int g0 = group * EPG;

    #pragma unroll 2
    for (int j = 0; j < EPG; j += 2) {
        const int iA = g0 + j;
        const int iX = iA + halfid;        // my half's edge slot
        const int sX = s_src[iX];
        const int dX = s_dst[iX];

        // gather my half's edge endpoints (16B per lane, 2 nodes)
        uint4 a = h16[(size_t)sX * 16 + sl];
        uint4 c = h16[(size_t)dX * 16 + sl];

        float ss = acc_sq8(a, c);
        ss += __shfl_xor(ss, 1);           // head sum (2 lanes per head)
        float tt = sqrtf(ss) * wmain;
        tt += __shfl_xor(tt, 2);           // sum 8 heads across the 16-half
        tt += __shfl_xor(tt, 4);
        tt += __shfl_xor(tt, 8);

        float distA = __shfl(tt, 0, 32);
        float distB = __shfl(tt, 16, 32);

        const bool nearA = fabsf(distA - m_c) < THETA;
        const bool nearB = fabsf(distB - m_c) < THETA;
        const unsigned long long bA = __ballot(nearA);
        const unsigned long long bB = __ballot(nearB);
        const bool refA = ((bA >> gsh) & 0xffffffffULL) != 0ULL;
        const bool refB = ((bB >> gsh) & 0xffffffffULL) != 0ULL;

        if (refA) {
            const int sA = __shfl(sX, 0, 32);
            const int dA = __shfl(dX, 0, 32);
            float4 fa = h32[(size_t)sA * 32 + lane];
            float4 fc = h32[(size_t)dA * 32 + lane];
            distA = edge_dist32(fa, fc, wref);
        }
        if (refB) {
            const int sB = __shfl(sX, 16, 32);
            const int dB = __shfl(dX, 16, 32);
            float4 fa = h32[(size_t)sB * 32 + lane];
            float4 fc = h32[(size_t)dB * 32 + lane];
            distB = edge_dist32(fa, fc, wref);
        }

        const float mA = distA - m_c;
        const float mB = distB - m_c;
        const long long eA = base + iA;
        if (eA < (long long)E)
            __builtin_nontemporal_store(1.0f / (mA * mA + bb),
                                        out + (size_t)eA * 32 + lane);
        if (eA + 1 < (long long)E)
            __builtin_nontemporal_store(1.0f / (mB * mB + bb),
                                        out + (size_t)(eA + 1) * 32 + lane);
    }
}

// fallback: pure-f32 direct path (proven R1)
__global__ __launch_bounds__(256) void score_kernel_f32(
    const float* __restrict__ h,
    const int* __restrict__ src,
    const int* __restrict__ dst,
    const float* __restrict__ ws,
    float* __restrict__ out,
    int E) {
    __shared__ float s_w[8];
    __shared__ float s_m[32];
    __shared__ float s_b;
    const int t = threadIdx.x;
    if (t < 8)  s_w[t] = ws[t];
    if (t < 32) s_m[t] = ws[8 + t];
    if (t == 0) s_b = ws[40];
    __syncthreads();
    const int lane32 = t & 31;
    const int group  = t >> 5;
    const int gid    = blockIdx.x * 8 + group;
    const int stride = gridDim.x * 8;
    const float wgt  = s_w[lane32 >> 2];
    const float m_c  = s_m[lane32];
    const float bb   = s_b;
    for (int e = gid; e < E; e += stride) {
        const int si = src[e], di = dst[e];
        float4 a = ((const float4*)(h + (size_t)si * 128))[lane32];
        float4 c = ((const float4*)(h + (size_t)di * 128))[lane32];
        float tt = edge_dist32(a, c, wgt);
        float dm = tt - m_c;
        __builtin_nontemporal_store(1.0f / (dm * dm + bb),
                                    out + (size_t)e * 32 + lane32);
    }
}

extern "C" void kernel_launch(void* const* d_in, const int* in_sizes, int n_in,
                              void* d_out, int out_size, void* d_ws, size_t ws_size,
                              hipStream_t stream) {
    const float* h      = (const float*)d_in[0];
    const float* w      = (const float*)d_in[1];
    const float* r_dist = (const float*)d_in[2];
    const float* b      = (const float*)d_in[3];
    const int*   src    = (const int*)d_in[4];
    const int*   dst    = (const int*)d_in[5];
    float* out = (float*)d_out;
    float* ws  = (float*)d_ws;
    const int E = in_sizes[4];
    const int N = in_sizes[0] / 128;
    const long long nq = (long long)N * 16;

    const size_t need = 4096 + (size_t)N * 256;

    if (ws_size >= need) {
        uint4* h16 = (uint4*)((char*)d_ws + 4096);
        const int cvt_blocks = (int)((nq + 255) / 256);
        const int nblocks = (E + EPB - 1) / EPB;
        convert_kernel<<<cvt_blocks, 256, 0, stream>>>(h, w, r_dist, b, ws,
                                                       h16, nq);
        score_kernel<<<nblocks, 512, 0, stream>>>(h, h16, src, dst, ws, out, E);
    } else {
        param_kernel<<<1, 64, 0, stream>>>(w, r_dist, b, ws);
        score_kernel_f32<<<2048, 256, 0, stream>>>(h, src, dst, ws, out, E);
    }
}

// Round 8
// 225.706 us; speedup vs baseline: 5.0152x; 1.1042x over previous
//
#include <hip/hip_runtime.h>
#include <hip/hip_fp16.h>

#define EPSC  1e-4f
#define THETA 0.028f
#define EPB   2048   // edges per block (512 thr = 16 groups x 128 edges)
#define EPG   128    // edges per 32-lane group

typedef float  f4 __attribute__((ext_vector_type(4)));

// ws layout: float[0..7] softmax(w), float[8..39] m, float[40] b
//            byte 4096: h16 = N nodes x 128 dims fp16 (256 B/node)

__device__ __forceinline__ void write_params(const float* w, const float* r_dist,
                                             const float* b, float* ws) {
    float wm = w[0];
    #pragma unroll
    for (int i = 1; i < 8; ++i) wm = fmaxf(wm, w[i]);
    float e[8]; float s = 0.f;
    #pragma unroll
    for (int i = 0; i < 8; ++i) { e[i] = __expf(w[i] - wm); s += e[i]; }
    float inv = 1.0f / s;
    #pragma unroll
    for (int i = 0; i < 8; ++i) ws[i] = e[i] * inv;
    float acc = 0.f;
    for (int c = 0; c < 32; ++c) {
        acc += fabsf(r_dist[c] + EPSC) + EPSC;
        ws[8 + c] = fmaxf(acc, 0.f);
    }
    ws[40] = b[0];
}

__global__ void param_kernel(const float* __restrict__ w,
                             const float* __restrict__ r_dist,
                             const float* __restrict__ b,
                             float* __restrict__ ws) {
    if (blockIdx.x == 0 && threadIdx.x == 0) write_params(w, r_dist, b, ws);
}

// h -> fp16, node-major (256B/node). One thread = 8 dims = one uint4 out.
__global__ __launch_bounds__(256) void convert_kernel(
    const float* __restrict__ h,
    const float* __restrict__ w,
    const float* __restrict__ r_dist,
    const float* __restrict__ b,
    float* __restrict__ ws,
    uint4* __restrict__ h16,
    long long nq) {          // nq = N*16 quads
    const long long i = (long long)blockIdx.x * 256 + threadIdx.x;
    if (i == 0) write_params(w, r_dist, b, ws);
    if (i < nq) {
        const float4* p = (const float4*)h + i * 2;
        float4 v0 = p[0], v1 = p[1];
        __half2 x;
        uint4 o;
        x = __floats2half2_rn(v0.x, v0.y); o.x = *(unsigned*)&x;
        x = __floats2half2_rn(v0.z, v0.w); o.y = *(unsigned*)&x;
        x = __floats2half2_rn(v1.x, v1.y); o.z = *(unsigned*)&x;
        x = __floats2half2_rn(v1.z, v1.w); o.w = *(unsigned*)&x;
        h16[i] = o;
    }
}

__device__ __forceinline__ float acc_sq8(uint4 a, uint4 b) {
    float ss = 0.f;
    const unsigned* pa = &a.x;
    const unsigned* pb = &b.x;
    #pragma unroll
    for (int i = 0; i < 4; ++i) {
        float2 fa = __half22float2(*(const __half2*)&pa[i]);
        float2 fb = __half22float2(*(const __half2*)&pb[i]);
        float d0 = fa.x - fb.x, d1 = fa.y - fb.y;
        ss += d0 * d0 + d1 * d1;
    }
    return ss;
}

__device__ __forceinline__ float edge_dist32v(f4 a, f4 c, float wgt) {
    float dx = c.x - a.x, dy = c.y - a.y, dz = c.z - a.z, dw = c.w - a.w;
    float ss = dx * dx + dy * dy + dz * dz + dw * dw;
    ss += __shfl_xor(ss, 1);
    ss += __shfl_xor(ss, 2);
    float t = sqrtf(ss) * wgt;
    t += __shfl_xor(t, 4);
    t += __shfl_xor(t, 8);
    t += __shfl_xor(t, 16);
    return t;
}

__device__ __forceinline__ float edge_dist32(float4 a, float4 c, float wgt) {
    float dx = c.x - a.x, dy = c.y - a.y, dz = c.z - a.z, dw = c.w - a.w;
    float ss = dx * dx + dy * dy + dz * dz + dw * dw;
    ss += __shfl_xor(ss, 1);
    ss += __shfl_xor(ss, 2);
    float t = sqrtf(ss) * wgt;
    t += __shfl_xor(t, 4);
    t += __shfl_xor(t, 8);
    t += __shfl_xor(t, 16);
    return t;
}

// One 32-lane group processes TWO edges per iteration (lanes 0-15 edge A,
// 16-31 edge B), 2-deep software pipeline: next pair's 4 gathers issued
// before computing the current pair (shfl compute overlaps vmcnt loads).
__global__ __launch_bounds__(512) void score_kernel(
    const float* __restrict__ h,
    const uint4* __restrict__ h16,
    const int* __restrict__ src,
    const int* __restrict__ dst,
    const float* __restrict__ ws,
    float* __restrict__ out,
    int E) {
    __shared__ int s_src[EPB];
    __shared__ int s_dst[EPB];
    __shared__ float s_w[8];
    __shared__ float s_m[32];
    __shared__ float s_b;

    const int t = threadIdx.x;
    if (t < 8)  s_w[t] = ws[t];
    if (t < 32) s_m[t] = ws[8 + t];
    if (t == 0) s_b = ws[40];

    const long long base = (long long)blockIdx.x * EPB;
    if (base + EPB <= (long long)E) {
        ((int4*)s_src)[t] = ((const int4*)(src + base))[t];
        ((int4*)s_dst)[t] = ((const int4*)(dst + base))[t];
    } else {
        for (int i = t; i < EPB; i += 512) {
            long long e = base + i;
            s_src[i] = (e < (long long)E) ? src[e] : 0;
            s_dst[i] = (e < (long long)E) ? dst[e] : 0;
        }
    }
    __syncthreads();

    const int lane   = t & 31;        // lane within 32-group
    const int sl     = lane & 15;     // sub-lane within 16-half
    const int halfid = lane >> 4;     // 0 = edge A, 1 = edge B
    const int group  = t >> 5;        // 16 groups per block
    const int gsh    = t & 32;        // this group's shift in the wave ballot

    const float wmain = s_w[sl >> 1];     // main path: 2 lanes per head
    const float wref  = s_w[lane >> 2];   // refine path: 4 lanes per head
    const float m_c   = s_m[lane];
    const float bb    = s_b;
    const f4* h4 = (const f4*)h;

    const int g0 = group * EPG;

    // pipeline prologue: issue pair 0's gathers
    int sX = s_src[g0 + halfid];
    int dX = s_dst[g0 + halfid];
    uint4 a = h16[(size_t)sX * 16 + sl];
    uint4 c = h16[(size_t)dX * 16 + sl];

    for (int j = 0; j < EPG; j += 2) {
        // issue next pair's gathers (clamped at the end)
        const int jn = (j + 2 < EPG) ? j + 2 : j;
        const int sN = s_src[g0 + jn + halfid];
        const int dN = s_dst[g0 + jn + halfid];
        uint4 an = h16[(size_t)sN * 16 + sl];
        uint4 cn = h16[(size_t)dN * 16 + sl];

        // ---- compute current pair ----
        float ss = acc_sq8(a, c);
        ss += __shfl_xor(ss, 1);           // head sum (2 lanes per head)
        float tt = sqrtf(ss) * wmain;
        tt += __shfl_xor(tt, 2);           // sum 8 heads across the 16-half
        tt += __shfl_xor(tt, 4);
        tt += __shfl_xor(tt, 8);

        float distA = __shfl(tt, 0, 32);
        float distB = __shfl(tt, 16, 32);

        const bool nearA = fabsf(distA - m_c) < THETA;
        const bool nearB = fabsf(distB - m_c) < THETA;
        const unsigned long long bA = __ballot(nearA);
        const unsigned long long bB = __ballot(nearB);
        const bool refA = ((bA >> gsh) & 0xffffffffULL) != 0ULL;
        const bool refB = ((bB >> gsh) & 0xffffffffULL) != 0ULL;

        if (refA) {
            const int sA = __shfl(sX, 0, 32);
            const int dA = __shfl(dX, 0, 32);
            f4 fa = __builtin_nontemporal_load(&h4[(size_t)sA * 32 + lane]);
            f4 fc = __builtin_nontemporal_load(&h4[(size_t)dA * 32 + lane]);
            distA = edge_dist32v(fa, fc, wref);
        }
        if (refB) {
            const int sB = __shfl(sX, 16, 32);
            const int dB = __shfl(dX, 16, 32);
            f4 fa = __builtin_nontemporal_load(&h4[(size_t)sB * 32 + lane]);
            f4 fc = __builtin_nontemporal_load(&h4[(size_t)dB * 32 + lane]);
            distB = edge_dist32v(fa, fc, wref);
        }

        const float mA = distA - m_c;
        const float mB = distB - m_c;
        const long long eA = base + g0 + j;
        if (eA < (long long)E)
            __builtin_nontemporal_store(1.0f / (mA * mA + bb),
                                        out + (size_t)eA * 32 + lane);
        if (eA + 1 < (long long)E)
            __builtin_nontemporal_store(1.0f / (mB * mB + bb),
                                        out + (size_t)(eA + 1) * 32 + lane);

        // rotate pipeline registers
        sX = sN; dX = dN; a = an; c = cn;
    }
}

// fallback: pure-f32 direct path (proven R1)
__global__ __launch_bounds__(256) void score_kernel_f32(
    const float* __restrict__ h,
    const int* __restrict__ src,
    const int* __restrict__ dst,
    const float* __restrict__ ws,
    float* __restrict__ out,
    int E) {
    __shared__ float s_w[8];
    __shared__ float s_m[32];
    __shared__ float s_b;
    const int t = threadIdx.x;
    if (t < 8)  s_w[t] = ws[t];
    if (t < 32) s_m[t] = ws[8 + t];
    if (t == 0) s_b = ws[40];
    __syncthreads();
    const int lane32 = t & 31;
    const int group  = t >> 5;
    const int gid    = blockIdx.x * 8 + group;
    const int stride = gridDim.x * 8;
    const float wgt  = s_w[lane32 >> 2];
    const float m_c  = s_m[lane32];
    const float bb   = s_b;
    for (int e = gid; e < E; e += stride) {
        const int si = src[e], di = dst[e];
        float4 a = ((const float4*)(h + (size_t)si * 128))[lane32];
        float4 c = ((const float4*)(h + (size_t)di * 128))[lane32];
        float tt = edge_dist32(a, c, wgt);
        float dm = tt - m_c;
        __builtin_nontemporal_store(1.0f / (dm * dm + bb),
                                    out + (size_t)e * 32 + lane32);
    }
}

extern "C" void kernel_launch(void* const* d_in, const int* in_sizes, int n_in,
                              void* d_out, int out_size, void* d_ws, size_t ws_size,
                              hipStream_t stream) {
    const float* h      = (const float*)d_in[0];
    const float* w      = (const float*)d_in[1];
    const float* r_dist = (const float*)d_in[2];
    const float* b      = (const float*)d_in[3];
    const int*   src    = (const int*)d_in[4];
    const int*   dst    = (const int*)d_in[5];
    float* out = (float*)d_out;
    float* ws  = (float*)d_ws;
    const int E = in_sizes[4];
    const int N = in_sizes[0] / 128;
    const long long nq = (long long)N * 16;

    const size_t need = 4096 + (size_t)N * 256;

    if (ws_size >= need) {
        uint4* h16 = (uint4*)((char*)d_ws + 4096);
        const int cvt_blocks = (int)((nq + 255) / 256);
        const int nblocks = (E + EPB - 1) / EPB;
        convert_kernel<<<cvt_blocks, 256, 0, stream>>>(h, w, r_dist, b, ws,
                                                       h16, nq);
        score_kernel<<<nblocks, 512, 0, stream>>>(h, h16, src, dst, ws, out, E);
    } else {
        param_kernel<<<1, 64, 0, stream>>>(w, r_dist, b, ws);
        score_kernel_f32<<<2048, 256, 0, stream>>>(h, src, dst, ws, out, E);
    }
}

// Round 9
// 189.654 us; speedup vs baseline: 5.9686x; 1.1901x over previous
//
#include <hip/hip_runtime.h>
#include <hip/hip_fp16.h>

#define EPSC  1e-4f
#define THETA 0.05f
#define EPB   2048   // edges per block (512 thr = 16 groups x 128 edges)
#define EPG   128    // edges per 32-lane group

typedef float f4 __attribute__((ext_vector_type(4)));

#if defined(__has_builtin)
#  if __has_builtin(__builtin_amdgcn_sdot4)
#    define SDOT4(a, b, c) __builtin_amdgcn_sdot4((int)(a), (int)(b), (c), false)
#  endif
#endif
#ifndef SDOT4
static __device__ __forceinline__ int sdot4_sw(unsigned a, unsigned b, int c) {
    #pragma unroll
    for (int k = 0; k < 4; ++k) {
        int ai = (int)(signed char)(a >> (8 * k));
        int bi = (int)(signed char)(b >> (8 * k));
        c += ai * bi;
    }
    return c;
}
#  define SDOT4(a, b, c) sdot4_sw((a), (b), (c))
#endif

// ws layout:
//   float[0..7] softmax(w), float[8..39] m, float[40] b
//   byte 4096:            scales  f32[N]
//   off_q8 (256-aligned): q8      N x 128 B (int8, per-node scale)
//   off_r16:              resid16 N x 256 B (fp16 of h - s*q)

__device__ __forceinline__ void write_params(const float* w, const float* r_dist,
                                             const float* b, float* ws) {
    float wm = w[0];
    #pragma unroll
    for (int i = 1; i < 8; ++i) wm = fmaxf(wm, w[i]);
    float e[8]; float s = 0.f;
    #pragma unroll
    for (int i = 0; i < 8; ++i) { e[i] = __expf(w[i] - wm); s += e[i]; }
    float inv = 1.0f / s;
    #pragma unroll
    for (int i = 0; i < 8; ++i) ws[i] = e[i] * inv;
    float acc = 0.f;
    for (int c = 0; c < 32; ++c) {
        acc += fabsf(r_dist[c] + EPSC) + EPSC;
        ws[8 + c] = fmaxf(acc, 0.f);
    }
    ws[40] = b[0];
}

__global__ void param_kernel(const float* __restrict__ w,
                             const float* __restrict__ r_dist,
                             const float* __restrict__ b,
                             float* __restrict__ ws) {
    if (blockIdx.x == 0 && threadIdx.x == 0) write_params(w, r_dist, b, ws);
}

// 16 threads per node: quantize to int8 with per-node scale + fp16 residual.
__global__ __launch_bounds__(256) void convert_kernel(
    const float* __restrict__ h,
    const float* __restrict__ w,
    const float* __restrict__ r_dist,
    const float* __restrict__ b,
    float* __restrict__ ws,
    float* __restrict__ scales,
    uint2* __restrict__ q8,      // 16 uint2 per node
    uint4* __restrict__ r16,     // 16 uint4 per node
    int N) {
    if (blockIdx.x == 0 && threadIdx.x == 0) write_params(w, r_dist, b, ws);
    const int node = blockIdx.x * 16 + (threadIdx.x >> 4);
    const int sl   = threadIdx.x & 15;
    if (node >= N) return;

    const float4* hp = (const float4*)(h + (size_t)node * 128 + sl * 8);
    float4 v0 = hp[0], v1 = hp[1];
    float va[8] = {v0.x, v0.y, v0.z, v0.w, v1.x, v1.y, v1.z, v1.w};

    float m = 0.f;
    #pragma unroll
    for (int k = 0; k < 8; ++k) m = fmaxf(m, fabsf(va[k]));
    m = fmaxf(m, __shfl_xor(m, 1));
    m = fmaxf(m, __shfl_xor(m, 2));
    m = fmaxf(m, __shfl_xor(m, 4));
    m = fmaxf(m, __shfl_xor(m, 8));
    m = fmaxf(m, 1e-30f);

    const float s   = m * (1.0f / 127.0f);
    const float inv = 127.0f / m;

    int q[8];
    #pragma unroll
    for (int k = 0; k < 8; ++k) q[k] = (int)rintf(va[k] * inv);

    uint2 qp;
    qp.x = (q[0] & 255) | ((q[1] & 255) << 8) | ((q[2] & 255) << 16) | ((q[3] & 255) << 24);
    qp.y = (q[4] & 255) | ((q[5] & 255) << 8) | ((q[6] & 255) << 16) | ((q[7] & 255) << 24);
    q8[(size_t)node * 16 + sl] = qp;

    uint4 rp;
    __half2 x;
    x = __floats2half2_rn(va[0] - s * q[0], va[1] - s * q[1]); rp.x = *(unsigned*)&x;
    x = __floats2half2_rn(va[2] - s * q[2], va[3] - s * q[3]); rp.y = *(unsigned*)&x;
    x = __floats2half2_rn(va[4] - s * q[4], va[5] - s * q[5]); rp.z = *(unsigned*)&x;
    x = __floats2half2_rn(va[6] - s * q[6], va[7] - s * q[7]); rp.w = *(unsigned*)&x;
    r16[(size_t)node * 16 + sl] = rp;

    if (sl == 0) scales[node] = s;
}

__device__ __forceinline__ float edge_dist32(float4 a, float4 c, float wgt) {
    float dx = c.x - a.x, dy = c.y - a.y, dz = c.z - a.z, dw = c.w - a.w;
    float ss = dx * dx + dy * dy + dz * dz + dw * dw;
    ss += __shfl_xor(ss, 1);
    ss += __shfl_xor(ss, 2);
    float t = sqrtf(ss) * wgt;
    t += __shfl_xor(t, 4);
    t += __shfl_xor(t, 8);
    t += __shfl_xor(t, 16);
    return t;
}

// Two edges per 32-lane group (lanes 0-15 edge A, 16-31 edge B).
// Main pass: int8 gather (one 128B line/node), exact integer dot via SDOT4.
// Refine (margin < THETA): fp16 residual gather, near-exact reconstruction.
__global__ __launch_bounds__(512) void score_kernel(
    const uint2* __restrict__ q8,
    const uint4* __restrict__ r16,
    const float* __restrict__ scales,
    const int* __restrict__ src,
    const int* __restrict__ dst,
    const float* __restrict__ ws,
    float* __restrict__ out,
    int E) {
    __shared__ int s_src[EPB];
    __shared__ int s_dst[EPB];
    __shared__ float s_w[8];
    __shared__ float s_m[32];
    __shared__ float s_b;

    const int t = threadIdx.x;
    if (t < 8)  s_w[t] = ws[t];
    if (t < 32) s_m[t] = ws[8 + t];
    if (t == 0) s_b = ws[40];

    const long long base = (long long)blockIdx.x * EPB;
    if (base + EPB <= (long long)E) {
        ((int4*)s_src)[t] = ((const int4*)(src + base))[t];
        ((int4*)s_dst)[t] = ((const int4*)(dst + base))[t];
    } else {
        for (int i = t; i < EPB; i += 512) {
            long long e = base + i;
            s_src[i] = (e < (long long)E) ? src[e] : 0;
            s_dst[i] = (e < (long long)E) ? dst[e] : 0;
        }
    }
    __syncthreads();

    const int lane   = t & 31;        // lane within 32-group
    const int sl     = lane & 15;     // sub-lane within 16-half
    const int halfid = lane >> 4;     // 0 = edge A, 1 = edge B
    const int hb     = halfid << 4;   // half base (0 or 16) within group
    const int group  = t >> 5;        // 16 groups per block
    const int gsh    = t & 32;        // group's shift in the wave ballot

    const float wmain = s_w[sl >> 1]; // 2 lanes per head
    const float m_c   = s_m[lane];
    const float bb    = s_b;

    const int g0 = group * EPG;

    // prologue: pair 0 loads
    int sX = s_src[g0 + halfid];
    int dX = s_dst[g0 + halfid];
    uint2 qs = q8[(size_t)sX * 16 + sl];
    uint2 qd = q8[(size_t)dX * 16 + sl];
    float sc0 = (sl < 2) ? scales[sl == 0 ? sX : dX] : 0.f;

    for (int j = 0; j < EPG; j += 2) {
        // issue next pair's gathers
        const int jn = (j + 2 < EPG) ? j + 2 : j;
        const int sN = s_src[g0 + jn + halfid];
        const int dN = s_dst[g0 + jn + halfid];
        uint2 qsn = q8[(size_t)sN * 16 + sl];
        uint2 qdn = q8[(size_t)dN * 16 + sl];
        float scn = (sl < 2) ? scales[sl == 0 ? sN : dN] : 0.f;

        // ---- compute current pair ----
        const float ssc = __shfl(sc0, hb + 0, 32);   // src scale of my half's edge
        const float sdc = __shfl(sc0, hb + 1, 32);   // dst scale

        int cx = SDOT4(qs.x, qd.x, 0); cx = SDOT4(qs.y, qd.y, cx);
        int sn2 = SDOT4(qs.x, qs.x, 0); sn2 = SDOT4(qs.y, qs.y, sn2);
        int dn2 = SDOT4(qd.x, qd.x, 0); dn2 = SDOT4(qd.y, qd.y, dn2);

        float part = ssc * ssc * (float)sn2 + sdc * sdc * (float)dn2
                   - 2.0f * ssc * sdc * (float)cx;
        part += __shfl_xor(part, 1);                 // per-head ||diff||^2
        float tt = sqrtf(fmaxf(part, 0.f)) * wmain;
        tt += __shfl_xor(tt, 2);                     // sum heads
        tt += __shfl_xor(tt, 4);
        tt += __shfl_xor(tt, 8);

        float distA = __shfl(tt, 0, 32);
        float distB = __shfl(tt, 16, 32);

        const bool nearA = fabsf(distA - m_c) < THETA;
        const bool nearB = fabsf(distB - m_c) < THETA;
        const unsigned long long bA = __ballot(nearA);
        const unsigned long long bB = __ballot(nearB);
        const bool refA = ((bA >> gsh) & 0xffffffffULL) != 0ULL;
        const bool refB = ((bB >> gsh) & 0xffffffffULL) != 0ULL;

        if (refA || refB) {
            const bool doref = halfid ? refB : refA;
            float ttr = 0.f;
            if (doref) {
                uint4 rs = r16[(size_t)sX * 16 + sl];
                uint4 rd = r16[(size_t)dX * 16 + sl];
                const __half2* rsp = (const __half2*)&rs;
                const __half2* rdp = (const __half2*)&rd;
                float acc = 0.f;
                #pragma unroll
                for (int k = 0; k < 8; ++k) {
                    const unsigned qsw = (k < 4) ? qs.x : qs.y;
                    const unsigned qdw = (k < 4) ? qd.x : qd.y;
                    const int qsk = (int)(signed char)(qsw >> (8 * (k & 3)));
                    const int qdk = (int)(signed char)(qdw >> (8 * (k & 3)));
                    float2 rsf = __half22float2(rsp[k >> 1]);
                    float2 rdf = __half22float2(rdp[k >> 1]);
                    const float rsk = (k & 1) ? rsf.y : rsf.x;
                    const float rdk = (k & 1) ? rdf.y : rdf.x;
                    const float d = (ssc * qsk + rsk) - (sdc * qdk + rdk);
                    acc += d * d;
                }
                acc += __shfl_xor(acc, 1);
                ttr = sqrtf(acc) * wmain;
                ttr += __shfl_xor(ttr, 2);
                ttr += __shfl_xor(ttr, 4);
                ttr += __shfl_xor(ttr, 8);
            }
            if (refA) distA = __shfl(ttr, 0, 32);
            if (refB) distB = __shfl(ttr, 16, 32);
        }

        const float mA = distA - m_c;
        const float mB = distB - m_c;
        const long long eA = base + g0 + j;
        if (eA < (long long)E)
            __builtin_nontemporal_store(1.0f / (mA * mA + bb),
                                        out + (size_t)eA * 32 + lane);
        if (eA + 1 < (long long)E)
            __builtin_nontemporal_store(1.0f / (mB * mB + bb),
                                        out + (size_t)(eA + 1) * 32 + lane);

        // rotate pipeline
        sX = sN; dX = dN; qs = qsn; qd = qdn; sc0 = scn;
    }
}

// fallback: pure-f32 direct path (proven R1)
__global__ __launch_bounds__(256) void score_kernel_f32(
    const float* __restrict__ h,
    const int* __restrict__ src,
    const int* __restrict__ dst,
    const float* __restrict__ ws,
    float* __restrict__ out,
    int E) {
    __shared__ float s_w[8];
    __shared__ float s_m[32];
    __shared__ float s_b;
    const int t = threadIdx.x;
    if (t < 8)  s_w[t] = ws[t];
    if (t < 32) s_m[t] = ws[8 + t];
    if (t == 0) s_b = ws[40];
    __syncthreads();
    const int lane32 = t & 31;
    const int group  = t >> 5;
    const int gid    = blockIdx.x * 8 + group;
    const int stride = gridDim.x * 8;
    const float wgt  = s_w[lane32 >> 2];
    const float m_c  = s_m[lane32];
    const float bb   = s_b;
    for (int e = gid; e < E; e += stride) {
        const int si = src[e], di = dst[e];
        float4 a = ((const float4*)(h + (size_t)si * 128))[lane32];
        float4 c = ((const float4*)(h + (size_t)di * 128))[lane32];
        float tt = edge_dist32(a, c, wgt);
        float dm = tt - m_c;
        __builtin_nontemporal_store(1.0f / (dm * dm + bb),
                                    out + (size_t)e * 32 + lane32);
    }
}

extern "C" void kernel_launch(void* const* d_in, const int* in_sizes, int n_in,
                              void* d_out, int out_size, void* d_ws, size_t ws_size,
                              hipStream_t stream) {
    const float* h      = (const float*)d_in[0];
    const float* w      = (const float*)d_in[1];
    const float* r_dist = (const float*)d_in[2];
    const float* b      = (const float*)d_in[3];
    const int*   src    = (const int*)d_in[4];
    const int*   dst    = (const int*)d_in[5];
    float* out = (float*)d_out;
    float* ws  = (float*)d_ws;
    const int E = in_sizes[4];
    const int N = in_sizes[0] / 128;

    const size_t off_scales = 4096;
    const size_t off_q8  = (off_scales + (size_t)N * 4 + 255) & ~(size_t)255;
    const size_t off_r16 = off_q8 + (size_t)N * 128;
    const size_t need    = off_r16 + (size_t)N * 256;

    if (ws_size >= need) {
        float* scales = (float*)((char*)d_ws + off_scales);
        uint2* q8     = (uint2*)((char*)d_ws + off_q8);
        uint4* r16    = (uint4*)((char*)d_ws + off_r16);
        const int cvt_blocks = (N + 15) / 16;
        const int nblocks = (E + EPB - 1) / EPB;
        convert_kernel<<<cvt_blocks, 256, 0, stream>>>(h, w, r_dist, b, ws,
                                                       scales, q8, r16, N);
        score_kernel<<<nblocks, 512, 0, stream>>>(q8, r16, scales, src, dst,
                                                  ws, out, E);
    } else {
        param_kernel<<<1, 64, 0, stream>>>(w, r_dist, b, ws);
        score_kernel_f32<<<2048, 256, 0, stream>>>(h, src, dst, ws, out, E);
    }
}